// Round 5
// baseline (2248.177 us; speedup 1.0000x reference)
//
#include <hip/hip_runtime.h>
#include <hip/hip_bf16.h>

// RNNModule: leaky ReLU RNN scan + output projection, MI355X (gfx950).
// r5: r4 geometry (16 blocks x 512 thr, BBLK=16) + double-buffered LDS h tile
//     (2x16KB) -> ONE lgkm-only barrier per step, h-writes overlap MFMA phase
//     (no pre-write barrier needed), NREG=48/NLDS=16 (weights LDS = 128KB,
//     total LDS exactly 160KB), per-row fused epilogue, s_setprio around MFMA.

typedef __attribute__((ext_vector_type(4))) float f32x4;
typedef __attribute__((ext_vector_type(8))) short s16x8;

constexpr int BB = 256, TT = 750, NN = 512, INN = 6, OUTN = 2, MLEN = 250;
constexpr int BBLK = 16;                 // batch rows per block
constexpr int NBLKS = BB / BBLK;         // 16 blocks, one per CU
constexpr int WPB = 8;                   // waves per block
constexpr int NSL = NN / WPB;            // 64 neurons per wave
constexpr int NREG = 48;                 // B-frags in registers (tiles tt=0..2)
constexpr int NLDS = 16;                 // B-frags in LDS (tile tt=3)
constexpr int HBUF = BBLK * NN * 2;      // 16 KB per h buffer (bf16, swizzled)
constexpr int WOFF = 2 * HBUF;           // 32 KB: weights region start
constexpr int WSTRIDE = NLDS * 1024;     // 16 KB per wave
constexpr int SMEM_BYTES = WOFF + WPB * WSTRIDE;   // 163840 B = 160 KB (full LDS)
constexpr int DRVELTS = NBLKS * WPB * 64 * 16;     // shorts per time step

__device__ __forceinline__ unsigned short f2bf(float f) {
    unsigned v = __float_as_uint(f);
    v += 0x7fffu + ((v >> 16) & 1u);     // RNE
    return (unsigned short)(v >> 16);
}
__device__ __forceinline__ float bf2f(unsigned short h) {
    return __uint_as_float(((unsigned)h) << 16);
}

// ---- pre-pass: drv[t][blk][wave][lane][16] bf16 = noise + u @ w_in^T ----
__global__ __launch_bounds__(256)
void drive_kernel(const float* __restrict__ u, const float* __restrict__ noise,
                  const float* __restrict__ w_in, unsigned short* __restrict__ drv)
{
    int gid = blockIdx.x * 256 + threadIdx.x;
    int t = gid >> 13;                           // 16 blk * 8 w * 64 lanes = 8192
    if (t >= TT - 1) return;
    int lane = gid & 63, w = (gid >> 6) & 7, blk = (gid >> 9) & 15;
    int qq = lane >> 4, lr = lane & 15;

    float wv[4][INN];
    #pragma unroll
    for (int tt = 0; tt < 4; ++tt) {
        int n = w * NSL + 16 * tt + lr;
        #pragma unroll
        for (int i = 0; i < INN; ++i) wv[tt][i] = w_in[n * INN + i];
    }
    alignas(16) unsigned short o[16];
    #pragma unroll
    for (int r = 0; r < 4; ++r) {
        int b = blk * BBLK + 4 * qq + r;
        const float* up = u + ((size_t)b * TT + t) * INN;
        float uv[INN];
        #pragma unroll
        for (int i = 0; i < INN; ++i) uv[i] = up[i];
        const float* np = noise + ((size_t)b * TT + t) * NN;
        #pragma unroll
        for (int tt = 0; tt < 4; ++tt) {
            int n = w * NSL + 16 * tt + lr;
            float d = np[n];
            #pragma unroll
            for (int i = 0; i < INN; ++i) d += uv[i] * wv[tt][i];
            o[tt * 4 + r] = f2bf(d);
        }
    }
    s16x8* dst = (s16x8*)(drv + (size_t)gid * 16);
    dst[0] = *(const s16x8*)&o[0];
    dst[1] = *(const s16x8*)&o[8];
}

// One RNN step: read h from buffer RB (0/1), write h_new into buffer WB.
// Single lgkm-only barrier at the end (dbuf: writes target the idle buffer).
#define STEP(RB, WB)                                                              \
  {                                                                               \
    const s16x8* dp = (const s16x8*)dptr;                                         \
    s16x8 dv0 = dp[0], dv1 = dp[1];                                               \
    dptr += DRVELTS;                                                              \
    const char* hbE = hE##RB;                                                     \
    const char* hbO = hO##RB;                                                     \
    f32x4 a0 = {0.f,0.f,0.f,0.f}, a1 = a0, a2 = a0, a3 = a0;                      \
    __builtin_amdgcn_s_setprio(1);                                                \
    _Pragma("unroll")                                                             \
    for (int kk = 0; kk < 16; ++kk) {                                             \
      s16x8 av = *(const s16x8*)(((kk & 1) ? hbO : hbE) + (kk << 6));             \
      a0 = __builtin_amdgcn_mfma_f32_16x16x32_bf16(av, breg[kk],      a0, 0,0,0); \
      a1 = __builtin_amdgcn_mfma_f32_16x16x32_bf16(av, breg[16 + kk], a1, 0,0,0); \
      a2 = __builtin_amdgcn_mfma_f32_16x16x32_bf16(av, breg[32 + kk], a2, 0,0,0); \
      a3 = __builtin_amdgcn_mfma_f32_16x16x32_bf16(                               \
               av, *(const s16x8*)(wbase + (kk << 10)), a3, 0, 0, 0);             \
    }                                                                             \
    __builtin_amdgcn_s_setprio(0);                                                \
    union { s16x8 v; unsigned short e[8]; } U0, U1;                               \
    U0.v = dv0; U1.v = dv1;                                                       \
    char* bufc = smem + (WB) * HBUF;                                              \
    _Pragma("unroll")                                                             \
    for (int r = 0; r < 4; ++r) {                                                 \
      float h0 = 0.8f * stl[0*4+r] + 0.2f * fmaxf(a0[r] + bf2f(U0.e[r]),     0.f);\
      float h1 = 0.8f * stl[1*4+r] + 0.2f * fmaxf(a1[r] + bf2f(U0.e[4 + r]), 0.f);\
      float h2 = 0.8f * stl[2*4+r] + 0.2f * fmaxf(a2[r] + bf2f(U1.e[r]),     0.f);\
      float h3 = 0.8f * stl[3*4+r] + 0.2f * fmaxf(a3[r] + bf2f(U1.e[4 + r]), 0.f);\
      stl[0*4+r] = h0; stl[1*4+r] = h1; stl[2*4+r] = h2; stl[3*4+r] = h3;         \
      __builtin_nontemporal_store(h0, rowp[r] + 0);                               \
      __builtin_nontemporal_store(h1, rowp[r] + 16);                              \
      __builtin_nontemporal_store(h2, rowp[r] + 32);                              \
      __builtin_nontemporal_store(h3, rowp[r] + 48);                              \
      __hip_bfloat162 p01 = __float22bfloat162_rn(make_float2(h0, h1));           \
      __hip_bfloat162 p23 = __float22bfloat162_rn(make_float2(h2, h3));           \
      unsigned q01 = *reinterpret_cast<unsigned*>(&p01);                          \
      unsigned q23 = *reinterpret_cast<unsigned*>(&p23);                          \
      *(unsigned short*)(bufc + ((LB ^ (unsigned)((0 ^ r) << 4)) + 1024 * r))     \
          = (unsigned short)q01;                                                  \
      *(unsigned short*)(bufc + ((LB ^ (unsigned)((2 ^ r) << 4)) + 1024 * r))     \
          = (unsigned short)(q01 >> 16);                                          \
      *(unsigned short*)(bufc + ((LB ^ (unsigned)((4 ^ r) << 4)) + 1024 * r))     \
          = (unsigned short)q23;                                                  \
      *(unsigned short*)(bufc + ((LB ^ (unsigned)((6 ^ r) << 4)) + 1024 * r))     \
          = (unsigned short)(q23 >> 16);                                          \
      rowp[r] += NN;                                                              \
    }                                                                             \
    asm volatile("s_waitcnt lgkmcnt(0)\n\ts_barrier" ::: "memory");               \
  }

// ---- persistent scan: 16 blocks x 8 waves, LDS-only h, 1 barrier/step ----
__global__ __launch_bounds__(512, 2)
void rnn_scan_kernel(const float* __restrict__ w_rec,
                     const unsigned short* __restrict__ drv,
                     float* __restrict__ states)
{
    extern __shared__ char smem[];
    const int tid = threadIdx.x;
    const int w = tid >> 6, lane = tid & 63;
    const int qq = lane >> 4, lr = lane & 15, p7 = lr & 7;
    const int blk = blockIdx.x;
    const int bg = blk * BBLK;

    // stage weights: frag (tt,kk): lane holds w_rec[n=64w+16tt+lr][32kk+8qq+j]
    s16x8 breg[NREG];
    #pragma unroll
    for (int tt = 0; tt < 4; ++tt) {
        #pragma unroll
        for (int kk = 0; kk < 16; ++kk) {
            const int f = tt * 16 + kk;
            const int n = w * NSL + 16 * tt + lr;
            const float* p = w_rec + (size_t)n * NN + 32 * kk + 8 * qq;
            f32x4 x0 = *(const f32x4*)p;
            f32x4 x1 = *(const f32x4*)(p + 4);
            union { s16x8 v; unsigned short s[8]; } fr;
            #pragma unroll
            for (int j = 0; j < 4; ++j) { fr.s[j] = f2bf(x0[j]); fr.s[4+j] = f2bf(x1[j]); }
            if (f < NREG) breg[f] = fr.v;
            else *(s16x8*)(smem + WOFF + w * WSTRIDE + (f - NREG) * 1024 + lane * 16) = fr.v;
        }
    }
    // zero both h buffers (h_0 = 0) and states[:,0,:] for our rows
    for (int i = tid; i < WOFF / 4; i += 512) ((unsigned*)smem)[i] = 0u;
    for (int i = tid; i < BBLK * NN; i += 512)
        states[(size_t)(bg + (i >> 9)) * TT * NN + (i & 511)] = 0.f;
    __syncthreads();

    float stl[16];
    #pragma unroll
    for (int i = 0; i < 16; ++i) stl[i] = 0.f;

    // A-read folded bases per buffer: addr(kk)=buf + lr*1024 + ((4kk+qq)^p7)<<4
    //   = base(E/O) + kk*64  (E for even kk, O for odd)
    const int rb64 = (p7 & 4) << 4;
    const int hbase0 = lr * 1024 + ((qq ^ (p7 & 3)) << 4);
    const char* hE0 = smem + hbase0 + rb64;
    const char* hO0 = smem + hbase0 - rb64;
    const char* hE1 = hE0 + HBUF;
    const char* hO1 = hO0 + HBUF;
    const char* wbase = smem + WOFF + w * WSTRIDE + lane * 16;

    // h-write folded base: addr(tt,r) = buf + (LB ^ (((2tt)^r)<<4)) + 1024r
    const int s0 = 8 * w + (lr >> 3);
    const unsigned LB = 4096u * qq + ((unsigned)(s0 ^ (4 * (qq & 1))) << 4) + 2 * (lr & 7);

    float* rowp[4];
    #pragma unroll
    for (int r = 0; r < 4; ++r)
        rowp[r] = states + ((size_t)(bg + 4 * qq + r) * TT + 1) * NN + w * NSL + lr;

    const unsigned short* dptr = drv + ((size_t)(blk * WPB + w) * 64 + lane) * 16;

    // steps 1..748 as pairs (step s reads buf[(s-1)&1]); tail step 749 reads buf0
    for (int s = 1; s < TT - 1; s += 2) {
        STEP(0, 1)
        STEP(1, 0)
    }
    STEP(0, 1)
}

// out[b,t,o] = sum_n states[b,t,n] * w_out[o,n]; one wave per (b,t) row
__global__ __launch_bounds__(256)
void proj_kernel(const float* __restrict__ states, const float* __restrict__ w_out,
                 float* __restrict__ outf)
{
    const int wv   = (blockIdx.x * blockDim.x + threadIdx.x) >> 6;
    const int lane = threadIdx.x & 63;
    const float* sp = states + (size_t)wv * NN + lane * 8;
    const float* w0 = w_out + lane * 8;
    const float* w1 = w_out + NN + lane * 8;
    float d0 = 0.f, d1 = 0.f;
    #pragma unroll
    for (int i = 0; i < 8; ++i) {
        float sv = sp[i];
        d0 += sv * w0[i];
        d1 += sv * w1[i];
    }
    #pragma unroll
    for (int off = 32; off > 0; off >>= 1) {
        d0 += __shfl_xor(d0, off);
        d1 += __shfl_xor(d1, off);
    }
    if (lane == 0) {
        outf[(size_t)wv * 2]     = d0;
        outf[(size_t)wv * 2 + 1] = d1;
    }
}

__global__ void mask_kernel(const int* __restrict__ mask, const float* __restrict__ outf,
                            float* __restrict__ outm)
{
    int idx = blockIdx.x * blockDim.x + threadIdx.x;
    if (idx >= BB * MLEN * OUTN) return;
    int o  = idx % OUTN;
    int jm = (idx / OUTN) % MLEN;
    int b  = idx / (OUTN * MLEN);
    int t  = mask[jm];
    outm[idx] = outf[((size_t)b * TT + t) * OUTN + o];
}

extern "C" void kernel_launch(void* const* d_in, const int* in_sizes, int n_in,
                              void* d_out, int out_size, void* d_ws, size_t ws_size,
                              hipStream_t stream)
{
    (void)in_sizes; (void)n_in; (void)out_size; (void)ws_size;
    const float* u     = (const float*)d_in[0];
    const float* noise = (const float*)d_in[1];
    const float* w_rec = (const float*)d_in[2];
    const float* w_in  = (const float*)d_in[3];
    const float* w_out = (const float*)d_in[4];
    const int*   mask  = (const int*)d_in[5];

    float* states = (float*)d_out;                          // [256][750][512]
    float* outm   = states + (size_t)BB * TT * NN;          // [256][250][2]
    float* outf   = outm + (size_t)BB * MLEN * OUTN;        // [256][750][2]

    unsigned short* drvpk = (unsigned short*)d_ws;          // 196.3 MB packed drive

    hipFuncSetAttribute((const void*)rnn_scan_kernel,
                        hipFuncAttributeMaxDynamicSharedMemorySize, SMEM_BYTES);

    drive_kernel<<<(TT - 1) * 32, 256, 0, stream>>>(u, noise, w_in, drvpk);
    rnn_scan_kernel<<<NBLKS, 512, SMEM_BYTES, stream>>>(w_rec, drvpk, states);
    proj_kernel<<<(BB * TT) / 4, 256, 0, stream>>>(states, w_out, outf);
    mask_kernel<<<(BB * MLEN * OUTN + 255) / 256, 256, 0, stream>>>(mask, outf, outm);
}

// Round 7
// 2055.039 us; speedup vs baseline: 1.0940x; 1.0940x over previous
//
#include <hip/hip_runtime.h>
#include <hip/hip_bf16.h>

// RNNModule: leaky ReLU RNN scan + output projection, MI355X (gfx950).
// r7: r4 base (16 blocks x 512 thr, BBLK=16, single 16KB h buffer, 2 lgkm-only
//     barriers/step, 47 reg-B-frags + 17 LDS-B-frags, builtin MFMA) + explicit
//     2-deep LDS prefetch rings for A-frags and LDS-B-frags (static-index
//     arrays -> registers; ~6 DS ops in flight, counted lgkmcnt waits).

typedef __attribute__((ext_vector_type(4))) float f32x4;
typedef __attribute__((ext_vector_type(8))) short s16x8;

constexpr int BB = 256, TT = 750, NN = 512, INN = 6, OUTN = 2, MLEN = 250;
constexpr int BBLK = 16;                 // batch rows per block
constexpr int NBLKS = BB / BBLK;         // 16 blocks, one per CU
constexpr int WPB = 8;                   // waves per block
constexpr int NSL = NN / WPB;            // 64 neurons per wave
constexpr int NREG = 47;                 // B-frags in registers (of 64)
constexpr int NLDS = 64 - NREG;          // 17 B-frags in LDS per wave
constexpr int HBYTES = BBLK * NN * 2;    // 16 KB h tile (bf16, swizzled)
constexpr int WOFF = HBYTES;             // weights region start
constexpr int SMEM_BYTES = WOFF + WPB * NLDS * 1024;   // 155648 B = 152 KB
constexpr int DRVELTS = NBLKS * WPB * 64 * 16;         // shorts per time step

__device__ __forceinline__ unsigned short f2bf(float f) {
    unsigned v = __float_as_uint(f);
    v += 0x7fffu + ((v >> 16) & 1u);     // RNE
    return (unsigned short)(v >> 16);
}
__device__ __forceinline__ float bf2f(unsigned short h) {
    return __uint_as_float(((unsigned)h) << 16);
}

// ---- pre-pass: drv[t][blk][wave][lane][16] bf16 = noise + u @ w_in^T ----
__global__ __launch_bounds__(256)
void drive_kernel(const float* __restrict__ u, const float* __restrict__ noise,
                  const float* __restrict__ w_in, unsigned short* __restrict__ drv)
{
    int gid = blockIdx.x * 256 + threadIdx.x;
    int t = gid >> 13;                           // 16 blk * 8 w * 64 lanes = 8192
    if (t >= TT - 1) return;
    int lane = gid & 63, w = (gid >> 6) & 7, blk = (gid >> 9) & 15;
    int qq = lane >> 4, lr = lane & 15;

    float wv[4][INN];
    #pragma unroll
    for (int tt = 0; tt < 4; ++tt) {
        int n = w * NSL + 16 * tt + lr;
        #pragma unroll
        for (int i = 0; i < INN; ++i) wv[tt][i] = w_in[n * INN + i];
    }
    alignas(16) unsigned short o[16];
    #pragma unroll
    for (int r = 0; r < 4; ++r) {
        int b = blk * BBLK + 4 * qq + r;
        const float* up = u + ((size_t)b * TT + t) * INN;
        float uv[INN];
        #pragma unroll
        for (int i = 0; i < INN; ++i) uv[i] = up[i];
        const float* np = noise + ((size_t)b * TT + t) * NN;
        #pragma unroll
        for (int tt = 0; tt < 4; ++tt) {
            int n = w * NSL + 16 * tt + lr;
            float d = np[n];
            #pragma unroll
            for (int i = 0; i < INN; ++i) d += uv[i] * wv[tt][i];
            o[tt * 4 + r] = f2bf(d);
        }
    }
    s16x8* dst = (s16x8*)(drv + (size_t)gid * 16);
    dst[0] = *(const s16x8*)&o[0];
    dst[1] = *(const s16x8*)&o[8];
}

// ---- persistent scan: 16 blocks x 8 waves, LDS-only h exchange ----
__global__ __launch_bounds__(512, 2)
void rnn_scan_kernel(const float* __restrict__ w_rec,
                     const unsigned short* __restrict__ drv,
                     float* __restrict__ states)
{
    extern __shared__ char smem[];
    const int tid = threadIdx.x;
    const int w = tid >> 6, lane = tid & 63;
    const int qq = lane >> 4, lr = lane & 15, p7 = lr & 7;
    const int blk = blockIdx.x;
    const int bg = blk * BBLK;

    // stage weights: frag (tt,kk): lane holds w_rec[n=64w+16tt+lr][32kk+8qq+j]
    s16x8 breg[NREG];
    #pragma unroll
    for (int tt = 0; tt < 4; ++tt) {
        #pragma unroll
        for (int kk = 0; kk < 16; ++kk) {
            const int f = tt * 16 + kk;
            const int n = w * NSL + 16 * tt + lr;
            const float* p = w_rec + (size_t)n * NN + 32 * kk + 8 * qq;
            f32x4 x0 = *(const f32x4*)p;
            f32x4 x1 = *(const f32x4*)(p + 4);
            union { s16x8 v; unsigned short s[8]; } fr;
            #pragma unroll
            for (int j = 0; j < 4; ++j) { fr.s[j] = f2bf(x0[j]); fr.s[4+j] = f2bf(x1[j]); }
            if (f < NREG) breg[f] = fr.v;
            else *(s16x8*)(smem + WOFF + (w * NLDS + (f - NREG)) * 1024 + lane * 16) = fr.v;
        }
    }
    // zero h buffer (h_0 = 0) and states[:,0,:] for our rows
    for (int i = tid; i < HBYTES / 4; i += 512) ((unsigned*)smem)[i] = 0u;
    for (int i = tid; i < BBLK * NN; i += 512)
        states[(size_t)(bg + (i >> 9)) * TT * NN + (i & 511)] = 0.f;
    __syncthreads();

    float stl[16];
    #pragma unroll
    for (int i = 0; i < 16; ++i) stl[i] = 0.f;

    // A-read folded bases: addr(kk) = lr*1024 + ((4kk+qq)^p7)<<4 = base(E/O) + 64kk
    const int rb64 = (p7 & 4) << 4;
    const int hbase0 = lr * 1024 + ((qq ^ (p7 & 3)) << 4);
    const char* hbE = smem + hbase0 + rb64;
    const char* hbO = smem + hbase0 - rb64;
    const char* wbase = smem + WOFF + w * (NLDS * 1024) + lane * 16;

    // h-write folded base: addr(tt,r) = (LB ^ (((2tt)^r)<<4)) + 1024r
    const int s0 = 8 * w + (lr >> 3);
    const unsigned LB = 4096u * qq + ((unsigned)(s0 ^ (4 * (qq & 1))) << 4) + 2 * (lr & 7);

    float* rowp[4];
    #pragma unroll
    for (int r = 0; r < 4; ++r)
        rowp[r] = states + ((size_t)(bg + 4 * qq + r) * TT + 1) * NN + w * NSL + lr;

    const unsigned short* dptr = drv + ((size_t)(blk * WPB + w) * 64 + lane) * 16;

    for (int s = 1; s < TT; ++s) {
        // depth-0 drive load: consumed ~2500 cyc later in the epilogue
        const s16x8* dp = (const s16x8*)dptr;
        s16x8 dv0 = dp[0], dv1 = dp[1];
        dptr += DRVELTS;

        f32x4 a0 = {0.f,0.f,0.f,0.f}, a1 = a0, a2 = a0, a3 = a0;

        // 2-deep prefetch rings: av[kk] issued 2 iters ahead; bl[i] (LDS B-frags,
        // i=0..16; a2@kk15 uses bl[0], a3@kk uses bl[kk+1]) issued 2 ahead.
        s16x8 av[16];
        s16x8 bl[NLDS];
        av[0] = *(const s16x8*)(hbE + (0 << 6));
        av[1] = *(const s16x8*)(hbO + (1 << 6));
        bl[0] = *(const s16x8*)(wbase);
        bl[1] = *(const s16x8*)(wbase + (1 << 10));
        bl[2] = *(const s16x8*)(wbase + (2 << 10));
        #pragma unroll
        for (int kk = 0; kk < 16; ++kk) {
            if (kk + 2 < 16)
                av[kk + 2] = *(const s16x8*)((((kk + 2) & 1) ? hbO : hbE) + ((kk + 2) << 6));
            if (kk + 3 < NLDS)
                bl[kk + 3] = *(const s16x8*)(wbase + ((kk + 3) << 10));
            a0 = __builtin_amdgcn_mfma_f32_16x16x32_bf16(av[kk], breg[kk],      a0, 0,0,0);
            a1 = __builtin_amdgcn_mfma_f32_16x16x32_bf16(av[kk], breg[16 + kk], a1, 0,0,0);
            if (kk < 15)
                a2 = __builtin_amdgcn_mfma_f32_16x16x32_bf16(av[kk], breg[32+kk], a2, 0,0,0);
            else
                a2 = __builtin_amdgcn_mfma_f32_16x16x32_bf16(av[kk], bl[0], a2, 0,0,0);
            a3 = __builtin_amdgcn_mfma_f32_16x16x32_bf16(av[kk], bl[kk + 1], a3, 0,0,0);
        }

        // ---- epilogue compute BEFORE the read-drain barrier (overlaps other
        //      waves' MFMA); only the LDS h-writes must wait for the barrier ----
        union { s16x8 v; unsigned short e[8]; } U0, U1;
        U0.v = dv0; U1.v = dv1;
        const f32x4 aX[4] = {a0, a1, a2, a3};
        float hnv[4][4];
        #pragma unroll
        for (int tt = 0; tt < 4; ++tt) {
            #pragma unroll
            for (int r = 0; r < 4; ++r) {
                float d = bf2f(tt < 2 ? U0.e[tt * 4 + r] : U1.e[(tt - 2) * 4 + r]);
                float pre = aX[tt][r] + d;
                float hn = 0.8f * stl[tt * 4 + r] + 0.2f * fmaxf(pre, 0.f);
                stl[tt * 4 + r] = hn;
                hnv[tt][r] = hn;
                __builtin_nontemporal_store(hn, rowp[r] + tt * 16);
            }
        }
        // pack pairs (tt even, tt odd) with one RNE cvt_pk each
        unsigned pk[8];
        #pragma unroll
        for (int p = 0; p < 2; ++p)
            #pragma unroll
            for (int r = 0; r < 4; ++r) {
                __hip_bfloat162 h2 = __float22bfloat162_rn(
                    make_float2(hnv[2 * p][r], hnv[2 * p + 1][r]));
                pk[p * 4 + r] = *reinterpret_cast<unsigned*>(&h2);
            }
        #pragma unroll
        for (int r = 0; r < 4; ++r) rowp[r] += NN;

        // barrier 1: all waves' A-reads drained -> safe to overwrite h
        asm volatile("s_waitcnt lgkmcnt(0)\n\ts_barrier" ::: "memory");

        #pragma unroll
        for (int tt = 0; tt < 4; ++tt) {
            #pragma unroll
            for (int r = 0; r < 4; ++r) {
                const unsigned C = (unsigned)(((2 * tt) ^ r) << 4);
                unsigned short hv = (tt & 1) ? (unsigned short)(pk[(tt >> 1) * 4 + r] >> 16)
                                             : (unsigned short)(pk[(tt >> 1) * 4 + r]);
                *(unsigned short*)(smem + ((LB ^ C) + 1024 * r)) = hv;
            }
        }
        // barrier 2: h writes visible -> next step may read
        asm volatile("s_waitcnt lgkmcnt(0)\n\ts_barrier" ::: "memory");
    }
}

// out[b,t,o] = sum_n states[b,t,n] * w_out[o,n]; one wave per (b,t) row
__global__ __launch_bounds__(256)
void proj_kernel(const float* __restrict__ states, const float* __restrict__ w_out,
                 float* __restrict__ outf)
{
    const int wv   = (blockIdx.x * blockDim.x + threadIdx.x) >> 6;
    const int lane = threadIdx.x & 63;
    const float* sp = states + (size_t)wv * NN + lane * 8;
    const float* w0 = w_out + lane * 8;
    const float* w1 = w_out + NN + lane * 8;
    float d0 = 0.f, d1 = 0.f;
    #pragma unroll
    for (int i = 0; i < 8; ++i) {
        float sv = sp[i];
        d0 += sv * w0[i];
        d1 += sv * w1[i];
    }
    #pragma unroll
    for (int off = 32; off > 0; off >>= 1) {
        d0 += __shfl_xor(d0, off);
        d1 += __shfl_xor(d1, off);
    }
    if (lane == 0) {
        outf[(size_t)wv * 2]     = d0;
        outf[(size_t)wv * 2 + 1] = d1;
    }
}

__global__ void mask_kernel(const int* __restrict__ mask, const float* __restrict__ outf,
                            float* __restrict__ outm)
{
    int idx = blockIdx.x * blockDim.x + threadIdx.x;
    if (idx >= BB * MLEN * OUTN) return;
    int o  = idx % OUTN;
    int jm = (idx / OUTN) % MLEN;
    int b  = idx / (OUTN * MLEN);
    int t  = mask[jm];
    outm[idx] = outf[((size_t)b * TT + t) * OUTN + o];
}

extern "C" void kernel_launch(void* const* d_in, const int* in_sizes, int n_in,
                              void* d_out, int out_size, void* d_ws, size_t ws_size,
                              hipStream_t stream)
{
    (void)in_sizes; (void)n_in; (void)out_size; (void)ws_size;
    const float* u     = (const float*)d_in[0];
    const float* noise = (const float*)d_in[1];
    const float* w_rec = (const float*)d_in[2];
    const float* w_in  = (const float*)d_in[3];
    const float* w_out = (const float*)d_in[4];
    const int*   mask  = (const int*)d_in[5];

    float* states = (float*)d_out;                          // [256][750][512]
    float* outm   = states + (size_t)BB * TT * NN;          // [256][250][2]
    float* outf   = outm + (size_t)BB * MLEN * OUTN;        // [256][750][2]

    unsigned short* drvpk = (unsigned short*)d_ws;          // 196.3 MB packed drive

    hipFuncSetAttribute((const void*)rnn_scan_kernel,
                        hipFuncAttributeMaxDynamicSharedMemorySize, SMEM_BYTES);

    drive_kernel<<<(TT - 1) * 32, 256, 0, stream>>>(u, noise, w_in, drvpk);
    rnn_scan_kernel<<<NBLKS, 512, SMEM_BYTES, stream>>>(w_rec, drvpk, states);
    proj_kernel<<<(BB * TT) / 4, 256, 0, stream>>>(states, w_out, outf);
    mask_kernel<<<(BB * MLEN * OUTN + 255) / 256, 256, 0, stream>>>(mask, outf, outm);
}